// Round 5
// baseline (225.838 us; speedup 1.0000x reference)
//
#include <hip/hip_runtime.h>

// Trilinear 3D-LUT apply: lut [1,3,33,33,33] f32, x [8,3,1024,1024] f32 in [0,1)
// out [8,3,1024,1024] f32.
//
// V4: V3b data structure (fp16 b-pair LDS, 2x ds_read2_b32/pixel, v_dot2 b-lerp)
//     + software-pipelined x loads (prefetch next 2 float4-groups while computing
//     current 2) + hoisted per-block plane base.
//
// Diagnosis this round: V3b counters showed NOTHING saturated (HBM 41%, VALU 27%,
// LDS ~15%, occ 40%) -> latency-bound: serial load->gather->lerp chain per
// iteration, 16 waves/CU (LDS caps 1 block/CU) can't cover ~900cy HBM latency.
// Fix = ILP: keep 6 float4 loads in flight under each iteration's ~8-pixel
// compute; 8 independent gather chains per iteration.

#define D   33
#define D2  (33 * 33)
#define D3  (33 * 33 * 33)      // 35937
#define NP  (D3 - 1)            // fp16-pair entries: 35936 * 4 B = 143,744 B LDS
#define HW  (1024 * 1024)
#define QHW (HW / 4)            // float4 groups per plane = 2^18
#define NG  (8 * QHW)           // groups per channel
#define CHUNKS 256
#define GPC (NG / CHUNKS)       // groups per chunk = 8192
#define THREADS 1024
#define ITERS (GPC / THREADS)   // 8 groups per thread
#define PAIRS (ITERS / 2)       // 4 pipeline steps

typedef __fp16 h16;
typedef __attribute__((ext_vector_type(2))) __fp16 h16x2;
typedef __attribute__((ext_vector_type(4))) float f32x4;

#define DOT2(a, b) __builtin_amdgcn_fdot2((a), (b), 0.0f, false)

__global__ __launch_bounds__(THREADS) void lut3d_kernel(
    const float* __restrict__ lut, const float* __restrict__ x,
    float* __restrict__ out)
{
    const int c     = blockIdx.x;   // channel fastest: chunk-triple temporally adjacent
    const int chunk = blockIdx.y;

    // --- stage channel cube as fp16 b-pairs: ls[i] = (lut[i], lut[i+1]) -----
    __shared__ h16x2 ls[NP];
    {
        const float* lc = lut + c * D3;
        for (int i = threadIdx.x; i < NP; i += THREADS) {
            h16x2 v;
            v.x = (h16)lc[i];
            v.y = (h16)lc[i + 1];
            ls[i] = v;
        }
    }
    __syncthreads();

    const int tid  = threadIdx.x;
    const int base = chunk * GPC;           // chunk fits inside one batch plane
    const int bidx = base >> 18;            // batch index, block-constant
    const int pb   = (base & (QHW - 1)) * 4; // float offset of chunk in plane

    const float* xp = x   + (size_t)bidx * 3 * HW + pb;
    float*       op = out + (size_t)bidx * 3 * HW + (size_t)c * HW + pb;

    // compute+store one float4-group (4 pixels) at float-offset fo
    auto do_group = [&](int fo, float4 xr, float4 xg, float4 xB) {
        const float rr[4] = {xr.x, xr.y, xr.z, xr.w};
        const float gg[4] = {xg.x, xg.y, xg.z, xg.w};
        const float bb[4] = {xB.x, xB.y, xB.z, xB.w};
        float oo[4];
        #pragma unroll
        for (int j = 0; j < 4; ++j) {
            // clamp(x,0,1)*32 capped below 32: i0<=31 always -> +1/+33/+1089
            // neighbor offsets are compile-time constants.
            const float vr = fminf(fmaxf(rr[j], 0.f) * 32.f, 31.999998f);
            const float vg = fminf(fmaxf(gg[j], 0.f) * 32.f, 31.999998f);
            const float vb = fminf(fmaxf(bb[j], 0.f) * 32.f, 31.999998f);

            const int r0 = (int)vr, g0 = (int)vg, b0 = (int)vb;  // trunc==floor
            const float fb = vb - (float)b0;
            const float fg = vg - (float)g0;
            const float fr = vr - (float)r0;

            const int idx = __mul24(r0, D2) + __mul24(g0, D) + b0;

            // 4 dwords at const dword offsets {0,33} from bases idx, idx+1089
            // -> 2x ds_read2_b32
            const h16x2 h00 = ls[idx];            // (c000, c001)
            const h16x2 h01 = ls[idx + D];        // (c010, c011)
            const h16x2 h10 = ls[idx + D2];       // (c100, c101)
            const h16x2 h11 = ls[idx + D2 + D];   // (c110, c111)

            const h16x2 w = __builtin_amdgcn_cvt_pkrtz(1.0f - fb, fb);
            const float c00 = DOT2(h00, w);
            const float c01 = DOT2(h01, w);
            const float c10 = DOT2(h10, w);
            const float c11 = DOT2(h11, w);

            const float cg0 = c00 + fg * (c01 - c00);
            const float cg1 = c10 + fg * (c11 - c10);
            oo[j] = cg0 + fr * (cg1 - cg0);
        }
        f32x4 ov;
        ov.x = oo[0]; ov.y = oo[1]; ov.z = oo[2]; ov.w = oo[3];
        // write-once output: non-temporal, keep L2 for shared x lines
        __builtin_nontemporal_store(ov, (f32x4*)(op + fo));
    };

    // --- software pipeline: prefetch pair k+1 while computing pair k --------
    float4 a0, a1, a2, b0, b1, b2;
    {
        const int f0 = tid * 4;
        const int f1 = f0 + THREADS * 4;
        a0 = *(const float4*)(xp + f0);
        a1 = *(const float4*)(xp + f0 + HW);
        a2 = *(const float4*)(xp + f0 + 2 * HW);
        b0 = *(const float4*)(xp + f1);
        b1 = *(const float4*)(xp + f1 + HW);
        b2 = *(const float4*)(xp + f1 + 2 * HW);
    }

    #pragma unroll 1
    for (int pr = 0; pr < PAIRS; ++pr) {
        float4 n0, n1, n2, m0, m1, m2;
        if (pr + 1 < PAIRS) {               // uniform branch
            const int f0 = (2 * (pr + 1)) * (THREADS * 4) + tid * 4;
            const int f1 = f0 + THREADS * 4;
            n0 = *(const float4*)(xp + f0);
            n1 = *(const float4*)(xp + f0 + HW);
            n2 = *(const float4*)(xp + f0 + 2 * HW);
            m0 = *(const float4*)(xp + f1);
            m1 = *(const float4*)(xp + f1 + HW);
            m2 = *(const float4*)(xp + f1 + 2 * HW);
        }
        const int fo0 = (2 * pr) * (THREADS * 4) + tid * 4;
        do_group(fo0,                a0, a1, a2);
        do_group(fo0 + THREADS * 4,  b0, b1, b2);
        a0 = n0; a1 = n1; a2 = n2;
        b0 = m0; b1 = m1; b2 = m2;
    }
}

extern "C" void kernel_launch(void* const* d_in, const int* in_sizes, int n_in,
                              void* d_out, int out_size, void* d_ws, size_t ws_size,
                              hipStream_t stream) {
    const float* lut = (const float*)d_in[0];   // [1,3,33,33,33]
    const float* x   = (const float*)d_in[1];   // [8,3,1024,1024]
    float* out = (float*)d_out;                 // [8,3,1024,1024]

    dim3 grid(3, CHUNKS);
    lut3d_kernel<<<grid, THREADS, 0, stream>>>(lut, x, out);
}